// Round 4
// baseline (93.540 us; speedup 1.0000x reference)
//
#include <hip/hip_runtime.h>
#include <hip/hip_bf16.h>
#include <stdint.h>

#define BSZ 384
#define DD  256
#define NWAVES 6
#define NEG_BIG -3.0e38f

// ---------------- threefry2x32, key = (0, 42) = jax.random.key(42) -----------
__device__ __forceinline__ void threefry_0_42(uint32_t c0, uint32_t c1,
                                              uint32_t& o0, uint32_t& o1) {
    const uint32_t k0 = 0u;
    const uint32_t k1 = 42u;
    const uint32_t k2 = 0u ^ 42u ^ 0x1BD11BDAu;
    uint32_t x0 = c0 + k0;
    uint32_t x1 = c1 + k1;
#define TF_RND(R) { x0 += x1; x1 = (x1 << (R)) | (x1 >> (32 - (R))); x1 ^= x0; }
    TF_RND(13) TF_RND(15) TF_RND(26) TF_RND(6)
    x0 += k1; x1 += k2 + 1u;
    TF_RND(17) TF_RND(29) TF_RND(16) TF_RND(24)
    x0 += k2; x1 += k0 + 2u;
    TF_RND(13) TF_RND(15) TF_RND(26) TF_RND(6)
    x0 += k0; x1 += k1 + 3u;
    TF_RND(17) TF_RND(29) TF_RND(16) TF_RND(24)
    x0 += k1; x1 += k2 + 4u;
    TF_RND(13) TF_RND(15) TF_RND(26) TF_RND(6)
    x0 += k2; x1 += k0 + 5u;
#undef TF_RND
    o0 = x0; o1 = x1;
}

// gumbel[idx] as jax.random.gumbel(key(42), (B,B,B), f32) under
// jax_threefry_partitionable=True: cipher(0, idx), output = r0 ^ r1.
// (Bit-exact vs reference: rounds 2-3 absmax 0.0.)
__device__ __forceinline__ float gumbel_at(uint32_t idx) {
    uint32_t r0, r1;
    threefry_0_42(0u, idx, r0, r1);
    uint32_t bits = r0 ^ r1;
    uint32_t mant = bits >> 9;
    float f = __uint_as_float(mant | 0x3F800000u) - 1.0f; // exact in [0,1)
    float u = (mant == 0u) ? 1.17549435e-38f : f;         // minval = f32 tiny
    return -logf(-logf(u));
}

// One block per anchor i.
// Phase 1: wave-cooperative COALESCED dist row: wave w computes rows
//   k in [64w, 64w+64); per row one coalesced float4 wave-load of F[k,:]
//   (lane l takes dims 4l..4l+3) + 6-step shfl_xor butterfly sum.
//   (Round-3's per-thread gather had lanes 1 KB apart -> every wave-load
//    touched 64 cache lines; that scatter was the ~36 us.)
// Phase 2: barrier-free wave-per-pair semi-hard mining (validated round 3).
// Phase 3: last-done-block epilogue writes the final mean.
__global__ __launch_bounds__(BSZ) void fused_kernel(const float* __restrict__ F,
                                                    const int* __restrict__ labels,
                                                    const int* __restrict__ epochp,
                                                    float* __restrict__ total,
                                                    unsigned int* __restrict__ count,
                                                    unsigned int* __restrict__ done,
                                                    float* __restrict__ out) {
    __shared__ float    row[BSZ];     // dist(i, k)
    __shared__ float    nlog[BSZ];    // -log(dist(i,k)) (0 if epoch<=3)
    __shared__ int      slab[BSZ];    // labels
    __shared__ int      plist[BSZ];   // compact positive-j list
    __shared__ int      npos;
    __shared__ float    wtot[NWAVES];
    __shared__ unsigned wcnt[NWAVES];

    const int i    = blockIdx.x;
    const int tid  = threadIdx.x;
    const int wave = tid >> 6;
    const int lane = tid & 63;

    slab[tid] = labels[tid];
    if (tid == 0) npos = 0;
    __syncthreads();

    const int lab_i = slab[i];
    if (tid > i && slab[tid] == lab_i)
        plist[atomicAdd(&npos, 1)] = tid;   // order irrelevant: pairs independent
    const int  epoch   = *epochp;
    const bool semisel = (epoch > 3);
    __syncthreads();

    const int np = npos;
    float    t_total = 0.0f;
    unsigned t_count = 0u;

    if (np > 0) {
        // anchor fragment in registers: lane l holds F[i, 4l..4l+3]
        const float4 fi4 = ((const float4*)(F + (size_t)i * DD))[lane];
        const int base = wave * 64;
        float vrow = 0.0f;                 // lane r ends with dist(i, base+r)
        for (int r = 0; r < 64; ++r) {
            const int k = base + r;
            float4 b = ((const float4*)(F + (size_t)k * DD))[lane]; // coalesced
            float d0 = fi4.x - b.x;
            float d1 = fi4.y - b.y;
            float d2 = fi4.z - b.z;
            float d3 = fi4.w - b.w;
            float p = fmaf(d0, d0, fmaf(d1, d1, fmaf(d2, d2, d3 * d3)));
#pragma unroll
            for (int off = 1; off < 64; off <<= 1)
                p += __shfl_xor(p, off, 64);
            float dk = sqrtf(fmaxf(p, 1e-11f));
            vrow = (lane == r) ? dk : vrow;
        }
        row[base + lane]  = vrow;                                  // coalesced
        nlog[base + lane] = semisel ? -logf(vrow) : 0.0f;          // 1 log/lane
        __syncthreads();

        // wave w owns positive pairs p = w, w+6, ... — no barriers below
        for (int p = wave; p < np; p += NWAVES) {
            const int   j     = plist[p];
            const float d_pos = row[j];
            const float hi    = d_pos + 0.2f;
            float v  = NEG_BIG;
            int   kk = 0;
#pragma unroll
            for (int c = 0; c < BSZ / 64; ++c) {
                const int   k   = c * 64 + lane;
                const float dkk = row[k];
                const bool cand = (slab[k] != lab_i) &&
                                  (!semisel || (dkk > d_pos && dkk < hi));
                if (__any(cand)) {          // whole-chunk skip when no candidates
                    if (cand) {
                        const uint32_t idx = (uint32_t)(i * BSZ + j) * (uint32_t)BSZ
                                             + (uint32_t)k;
                        float val = nlog[k] + gumbel_at(idx);
                        if (val > v) { v = val; kk = k; }  // strict > keeps first max
                    }
                }
            }
            // wave argmax (val desc, idx asc — matches jnp.argmax first-max)
#pragma unroll
            for (int off = 32; off; off >>= 1) {
                float ov = __shfl_down(v, off, 64);
                int   oi = __shfl_down(kk, off, 64);
                if (ov > v || (ov == v && oi < kk)) { v = ov; kk = oi; }
            }
            if (lane == 0 && v > -1.0e38f) {  // has_neg
                t_total += fmaxf(d_pos - row[kk] + 0.2f, 0.0f);
                t_count += 1u;
            }
        }
    }

    if (lane == 0) { wtot[wave] = t_total; wcnt[wave] = t_count; }
    __syncthreads();
    if (tid == 0) {
        float    tt = 0.0f;
        unsigned cc = 0u;
#pragma unroll
        for (int q = 0; q < NWAVES; ++q) { tt += wtot[q]; cc += wcnt[q]; }
        if (cc) {
            atomicAdd(total, tt);
            atomicAdd(count, cc);
        }
        __threadfence();  // make our adds visible before signaling done
        const unsigned prev = atomicAdd(done, 1u);
        if (prev == (unsigned)gridDim.x - 1u) {
            const float    T = atomicAdd(total, 0.0f);
            const unsigned C = atomicAdd(count, 0u);
            out[0] = (C > 0u) ? (T / (float)C) : 0.0f;
        }
    }
}

extern "C" void kernel_launch(void* const* d_in, const int* in_sizes, int n_in,
                              void* d_out, int out_size, void* d_ws, size_t ws_size,
                              hipStream_t stream) {
    const float* F      = (const float*)d_in[0];
    const int*   labels = (const int*)d_in[1];
    const int*   epoch  = (const int*)d_in[2];
    float*       out    = (float*)d_out;

    if (ws_size < 12) return;  // safety
    float*        total = (float*)d_ws;
    unsigned int* count = (unsigned int*)d_ws + 1;
    unsigned int* done  = (unsigned int*)d_ws + 2;

    hipMemsetAsync(d_ws, 0, 12, stream);  // zero accumulators (ws is poisoned)
    fused_kernel<<<BSZ, BSZ, 0, stream>>>(F, labels, epoch, total, count, done, out);
}

// Round 5
// 79.282 us; speedup vs baseline: 1.1798x; 1.1798x over previous
//
#include <hip/hip_runtime.h>
#include <hip/hip_bf16.h>
#include <stdint.h>

#define BSZ 384
#define DD  256
#define NWAVES 6
#define NEG_BIG -3.0e38f

// ---------------- threefry2x32, key = (0, 42) = jax.random.key(42) -----------
__device__ __forceinline__ void threefry_0_42(uint32_t c0, uint32_t c1,
                                              uint32_t& o0, uint32_t& o1) {
    const uint32_t k0 = 0u;
    const uint32_t k1 = 42u;
    const uint32_t k2 = 0u ^ 42u ^ 0x1BD11BDAu;
    uint32_t x0 = c0 + k0;
    uint32_t x1 = c1 + k1;
#define TF_RND(R) { x0 += x1; x1 = (x1 << (R)) | (x1 >> (32 - (R))); x1 ^= x0; }
    TF_RND(13) TF_RND(15) TF_RND(26) TF_RND(6)
    x0 += k1; x1 += k2 + 1u;
    TF_RND(17) TF_RND(29) TF_RND(16) TF_RND(24)
    x0 += k2; x1 += k0 + 2u;
    TF_RND(13) TF_RND(15) TF_RND(26) TF_RND(6)
    x0 += k0; x1 += k1 + 3u;
    TF_RND(17) TF_RND(29) TF_RND(16) TF_RND(24)
    x0 += k1; x1 += k2 + 4u;
    TF_RND(13) TF_RND(15) TF_RND(26) TF_RND(6)
    x0 += k2; x1 += k0 + 5u;
#undef TF_RND
    o0 = x0; o1 = x1;
}

// gumbel[idx] as jax.random.gumbel(key(42), (B,B,B), f32) under
// jax_threefry_partitionable=True: cipher(0, idx), output = r0 ^ r1.
// (Bit-exact vs reference: rounds 2-4 absmax 0.0.)
__device__ __forceinline__ float gumbel_at(uint32_t idx) {
    uint32_t r0, r1;
    threefry_0_42(0u, idx, r0, r1);
    uint32_t bits = r0 ^ r1;
    uint32_t mant = bits >> 9;
    float f = __uint_as_float(mant | 0x3F800000u) - 1.0f; // exact in [0,1)
    float u = (mant == 0u) ? 1.17549435e-38f : f;         // minval = f32 tiny
    return -logf(-logf(u));
}

// ---------------- pairwise distances: 16x16 tiles (round-2 validated) --------
// 576 blocks (2.25/CU), zero cross-lane ops -> pure ILP, no serial chains.
// Block (0,0) also zeroes the global accumulators (replaces the memset node;
// stream order guarantees visibility to mine_kernel).
__global__ __launch_bounds__(256) void dist_kernel(const float* __restrict__ F,
                                                   float* __restrict__ dist,
                                                   float* __restrict__ total,
                                                   unsigned int* __restrict__ count,
                                                   unsigned int* __restrict__ done) {
    __shared__ float As[16][DD + 4];
    __shared__ float Bs[16][DD + 4];
    const int i0 = blockIdx.y * 16;
    const int j0 = blockIdx.x * 16;
    const int tid = threadIdx.x;

    if (blockIdx.x == 0 && blockIdx.y == 0 && tid == 0) {
        *total = 0.0f; *count = 0u; *done = 0u;   // ws is poisoned each call
    }

    // stage 16 rows of A and B (16 * 64 float4 each; 4 per thread), coalesced
    for (int t = tid; t < 16 * 64; t += 256) {
        const int r = t >> 6;
        const int c = (t & 63) << 2;
        float4 a = *(const float4*)&F[(i0 + r) * DD + c];
        float4 b = *(const float4*)&F[(j0 + r) * DD + c];
        *(float4*)&As[r][c] = a;
        *(float4*)&Bs[r][c] = b;
    }
    __syncthreads();

    const int tx = tid & 15;  // j within tile
    const int ty = tid >> 4;  // i within tile
    float a0 = 0.f, a1 = 0.f, a2 = 0.f, a3 = 0.f;
#pragma unroll 8
    for (int d = 0; d < DD; d += 4) {
        float4 av = *(const float4*)&As[ty][d];
        float4 bv = *(const float4*)&Bs[tx][d];
        float d0 = av.x - bv.x;
        float d1 = av.y - bv.y;
        float d2 = av.z - bv.z;
        float d3 = av.w - bv.w;
        a0 = fmaf(d0, d0, a0);
        a1 = fmaf(d1, d1, a1);
        a2 = fmaf(d2, d2, a2);
        a3 = fmaf(d3, d3, a3);
    }
    float s = (a0 + a1) + (a2 + a3);
    s = fmaxf(s, 1e-11f);
    dist[(i0 + ty) * BSZ + (j0 + tx)] = sqrtf(s);
}

// ---------------- mining: block per anchor, wave per pair, no serial chains --
__global__ __launch_bounds__(BSZ) void mine_kernel(const float* __restrict__ dist,
                                                   const int* __restrict__ labels,
                                                   const int* __restrict__ epochp,
                                                   float* __restrict__ total,
                                                   unsigned int* __restrict__ count,
                                                   unsigned int* __restrict__ done,
                                                   float* __restrict__ out) {
    __shared__ float    row[BSZ];     // dist(i, k)
    __shared__ float    nlog[BSZ];    // -log(dist(i,k)) (0 if epoch<=3)
    __shared__ int      slab[BSZ];    // labels
    __shared__ int      plist[BSZ];   // compact positive-j list
    __shared__ int      npos;
    __shared__ float    wtot[NWAVES];
    __shared__ unsigned wcnt[NWAVES];

    const int i    = blockIdx.x;
    const int tid  = threadIdx.x;
    const int wave = tid >> 6;
    const int lane = tid & 63;

    slab[tid] = labels[tid];
    if (tid == 0) npos = 0;
    __syncthreads();

    const int lab_i = slab[i];
    if (tid > i && slab[tid] == lab_i)
        plist[atomicAdd(&npos, 1)] = tid;   // order irrelevant: pairs independent
    const int  epoch   = *epochp;
    const bool semisel = (epoch > 3);
    __syncthreads();

    const int np = npos;
    float    t_total = 0.0f;
    unsigned t_count = 0u;

    if (np > 0) {
        const float dk = dist[i * BSZ + tid];   // coalesced, L2-hit
        row[tid]  = dk;
        nlog[tid] = semisel ? -logf(dk) : 0.0f;
        __syncthreads();

        // wave w owns positive pairs p = w, w+6, ... — no barriers below
        for (int p = wave; p < np; p += NWAVES) {
            const int   j     = plist[p];
            const float d_pos = row[j];
            const float hi    = d_pos + 0.2f;
            float v  = NEG_BIG;
            int   kk = 0;
#pragma unroll
            for (int c = 0; c < BSZ / 64; ++c) {
                const int   k   = c * 64 + lane;
                const float dkk = row[k];
                const bool cand = (slab[k] != lab_i) &&
                                  (!semisel || (dkk > d_pos && dkk < hi));
                if (__any(cand)) {          // whole-chunk skip when no candidates
                    if (cand) {
                        const uint32_t idx = (uint32_t)(i * BSZ + j) * (uint32_t)BSZ
                                             + (uint32_t)k;
                        float val = nlog[k] + gumbel_at(idx);
                        if (val > v) { v = val; kk = k; }  // strict > keeps first max
                    }
                }
            }
            // wave argmax (val desc, idx asc — matches jnp.argmax first-max)
#pragma unroll
            for (int off = 32; off; off >>= 1) {
                float ov = __shfl_down(v, off, 64);
                int   oi = __shfl_down(kk, off, 64);
                if (ov > v || (ov == v && oi < kk)) { v = ov; kk = oi; }
            }
            if (lane == 0 && v > -1.0e38f) {  // has_neg
                t_total += fmaxf(d_pos - row[kk] + 0.2f, 0.0f);
                t_count += 1u;
            }
        }
    }

    if (lane == 0) { wtot[wave] = t_total; wcnt[wave] = t_count; }
    __syncthreads();
    if (tid == 0) {
        float    tt = 0.0f;
        unsigned cc = 0u;
#pragma unroll
        for (int q = 0; q < NWAVES; ++q) { tt += wtot[q]; cc += wcnt[q]; }
        if (cc) {
            atomicAdd(total, tt);
            atomicAdd(count, cc);
        }
        __threadfence();  // make our adds visible before signaling done
        const unsigned prev = atomicAdd(done, 1u);
        if (prev == (unsigned)gridDim.x - 1u) {
            const float    T = atomicAdd(total, 0.0f);
            const unsigned C = atomicAdd(count, 0u);
            out[0] = (C > 0u) ? (T / (float)C) : 0.0f;
        }
    }
}

extern "C" void kernel_launch(void* const* d_in, const int* in_sizes, int n_in,
                              void* d_out, int out_size, void* d_ws, size_t ws_size,
                              hipStream_t stream) {
    const float* F      = (const float*)d_in[0];
    const int*   labels = (const int*)d_in[1];
    const int*   epoch  = (const int*)d_in[2];
    float*       out    = (float*)d_out;

    const size_t dist_bytes = (size_t)BSZ * BSZ * sizeof(float);
    if (ws_size < dist_bytes + 16) return;  // safety

    float*        dist  = (float*)d_ws;
    float*        total = (float*)((char*)d_ws + dist_bytes);
    unsigned int* count = (unsigned int*)(total + 1);
    unsigned int* done  = (unsigned int*)(total + 2);

    dist_kernel<<<dim3(BSZ / 16, BSZ / 16), 256, 0, stream>>>(F, dist, total, count, done);
    mine_kernel<<<BSZ, BSZ, 0, stream>>>(dist, labels, epoch, total, count, done, out);
}

// Round 6
// 79.013 us; speedup vs baseline: 1.1839x; 1.0034x over previous
//
#include <hip/hip_runtime.h>
#include <hip/hip_bf16.h>
#include <stdint.h>

#define BSZ 384
#define DD  256
#define NWAVES 6
#define NEG_BIG -3.0e38f

// ---------------- threefry2x32, key = (0, 42) = jax.random.key(42) -----------
__device__ __forceinline__ void threefry_0_42(uint32_t c0, uint32_t c1,
                                              uint32_t& o0, uint32_t& o1) {
    const uint32_t k0 = 0u;
    const uint32_t k1 = 42u;
    const uint32_t k2 = 0u ^ 42u ^ 0x1BD11BDAu;
    uint32_t x0 = c0 + k0;
    uint32_t x1 = c1 + k1;
#define TF_RND(R) { x0 += x1; x1 = (x1 << (R)) | (x1 >> (32 - (R))); x1 ^= x0; }
    TF_RND(13) TF_RND(15) TF_RND(26) TF_RND(6)
    x0 += k1; x1 += k2 + 1u;
    TF_RND(17) TF_RND(29) TF_RND(16) TF_RND(24)
    x0 += k2; x1 += k0 + 2u;
    TF_RND(13) TF_RND(15) TF_RND(26) TF_RND(6)
    x0 += k0; x1 += k1 + 3u;
    TF_RND(17) TF_RND(29) TF_RND(16) TF_RND(24)
    x0 += k1; x1 += k2 + 4u;
    TF_RND(13) TF_RND(15) TF_RND(26) TF_RND(6)
    x0 += k2; x1 += k0 + 5u;
#undef TF_RND
    o0 = x0; o1 = x1;
}

// gumbel[idx] as jax.random.gumbel(key(42), (B,B,B), f32) under
// jax_threefry_partitionable=True: cipher(0, idx), output = r0 ^ r1.
// (Bit-exact vs reference: rounds 2-5 absmax 0.0.)
__device__ __forceinline__ float gumbel_at(uint32_t idx) {
    uint32_t r0, r1;
    threefry_0_42(0u, idx, r0, r1);
    uint32_t bits = r0 ^ r1;
    uint32_t mant = bits >> 9;
    float f = __uint_as_float(mant | 0x3F800000u) - 1.0f; // exact in [0,1)
    float u = (mant == 0u) ? 1.17549435e-38f : f;         // minval = f32 tiny
    return -logf(-logf(u));
}

// One block per anchor i, 384 threads.
// Phase 1 (dist row, the part r3/r4 got wrong):
//   8 lanes per row: lane = rl*8+s (rl=lane>>3, s=lane&7). Wave w, chunk c
//   computes rows k = c*48 + w*8 + rl. Lane reads float4 j = t*8+s of row k:
//   per wave-load -> 8 rows x 128 B contiguous = 8 cache lines (coalescing
//   minimum for 1 KB). Reduction = 3 shfl_down steps, 8 rows in PARALLEL
//   (r3's scatter hit 64 lines/load; r4's butterfly was 64 serial 6-step
//   chains). F is L2-resident; aggregate traffic 147 MB ~ 4-5 us.
// Phase 2: barrier-free wave-per-pair semi-hard mining (validated r4/r5).
// Phase 3: last-done-block epilogue writes the final mean.
__global__ __launch_bounds__(BSZ) void fused_kernel(const float* __restrict__ F,
                                                    const int* __restrict__ labels,
                                                    const int* __restrict__ epochp,
                                                    float* __restrict__ total,
                                                    unsigned int* __restrict__ count,
                                                    unsigned int* __restrict__ done,
                                                    float* __restrict__ out) {
    __shared__ float    row[BSZ];     // dist(i, k)
    __shared__ float    nlog[BSZ];    // -log(dist(i,k)) (0 if epoch<=3)
    __shared__ int      slab[BSZ];    // labels
    __shared__ int      plist[BSZ];   // compact positive-j list
    __shared__ int      npos;
    __shared__ float    wtot[NWAVES];
    __shared__ unsigned wcnt[NWAVES];

    const int i    = blockIdx.x;
    const int tid  = threadIdx.x;
    const int wave = tid >> 6;
    const int lane = tid & 63;
    const int rl   = lane >> 3;   // local row within wave's 8-row group
    const int s    = lane & 7;    // sub-lane within row (8 lanes/row)

    slab[tid] = labels[tid];
    if (tid == 0) npos = 0;
    __syncthreads();

    const int lab_i = slab[i];
    if (tid > i && slab[tid] == lab_i)
        plist[atomicAdd(&npos, 1)] = tid;   // order irrelevant: pairs independent
    const int  epoch   = *epochp;
    const bool semisel = (epoch > 3);
    __syncthreads();

    const int np = npos;
    float    t_total = 0.0f;
    unsigned t_count = 0u;

    if (np > 0) {   // np is block-uniform -> barriers below are safe
        const float4* F4 = (const float4*)F;

        // anchor fragments: this thread's 8 float4s of row i (reused 8 chunks)
        float4 fi[8];
#pragma unroll
        for (int t = 0; t < 8; ++t) fi[t] = F4[i * (DD / 4) + t * 8 + s];

        for (int c = 0; c < 8; ++c) {
            const int k = c * 48 + wave * 8 + rl;
            const float4* fk = F4 + (size_t)k * (DD / 4);
            float a0 = 0.f, a1 = 0.f, a2 = 0.f, a3 = 0.f;
#pragma unroll
            for (int t = 0; t < 8; ++t) {
                float4 b = fk[t * 8 + s];
                float d0 = fi[t].x - b.x;
                float d1 = fi[t].y - b.y;
                float d2 = fi[t].z - b.z;
                float d3 = fi[t].w - b.w;
                a0 = fmaf(d0, d0, a0);
                a1 = fmaf(d1, d1, a1);
                a2 = fmaf(d2, d2, a2);
                a3 = fmaf(d3, d3, a3);
            }
            float p = (a0 + a1) + (a2 + a3);
            p += __shfl_down(p, 4, 64);   // 8-lane tree, 8 rows in parallel
            p += __shfl_down(p, 2, 64);
            p += __shfl_down(p, 1, 64);
            if (s == 0) row[k] = sqrtf(fmaxf(p, 1e-11f));
        }
        __syncthreads();
        nlog[tid] = semisel ? -logf(row[tid]) : 0.0f;
        __syncthreads();

        // wave w owns positive pairs p = w, w+6, ... — no barriers below
        for (int p = wave; p < np; p += NWAVES) {
            const int   j     = plist[p];
            const float d_pos = row[j];
            const float hi    = d_pos + 0.2f;
            float v  = NEG_BIG;
            int   kk = 0;
#pragma unroll
            for (int c = 0; c < BSZ / 64; ++c) {
                const int   k   = c * 64 + lane;
                const float dkk = row[k];
                const bool cand = (slab[k] != lab_i) &&
                                  (!semisel || (dkk > d_pos && dkk < hi));
                if (__any(cand)) {          // whole-chunk skip when no candidates
                    if (cand) {
                        const uint32_t idx = (uint32_t)(i * BSZ + j) * (uint32_t)BSZ
                                             + (uint32_t)k;
                        float val = nlog[k] + gumbel_at(idx);
                        if (val > v) { v = val; kk = k; }  // strict > keeps first max
                    }
                }
            }
            // wave argmax (val desc, idx asc — matches jnp.argmax first-max)
#pragma unroll
            for (int off = 32; off; off >>= 1) {
                float ov = __shfl_down(v, off, 64);
                int   oi = __shfl_down(kk, off, 64);
                if (ov > v || (ov == v && oi < kk)) { v = ov; kk = oi; }
            }
            if (lane == 0 && v > -1.0e38f) {  // has_neg
                t_total += fmaxf(d_pos - row[kk] + 0.2f, 0.0f);
                t_count += 1u;
            }
        }
    }

    if (lane == 0) { wtot[wave] = t_total; wcnt[wave] = t_count; }
    __syncthreads();
    if (tid == 0) {
        float    tt = 0.0f;
        unsigned cc = 0u;
#pragma unroll
        for (int q = 0; q < NWAVES; ++q) { tt += wtot[q]; cc += wcnt[q]; }
        if (cc) {
            atomicAdd(total, tt);
            atomicAdd(count, cc);
        }
        __threadfence();  // make our adds visible before signaling done
        const unsigned prev = atomicAdd(done, 1u);
        if (prev == (unsigned)gridDim.x - 1u) {
            const float    T = atomicAdd(total, 0.0f);
            const unsigned C = atomicAdd(count, 0u);
            out[0] = (C > 0u) ? (T / (float)C) : 0.0f;
        }
    }
}

extern "C" void kernel_launch(void* const* d_in, const int* in_sizes, int n_in,
                              void* d_out, int out_size, void* d_ws, size_t ws_size,
                              hipStream_t stream) {
    const float* F      = (const float*)d_in[0];
    const int*   labels = (const int*)d_in[1];
    const int*   epoch  = (const int*)d_in[2];
    float*       out    = (float*)d_out;

    if (ws_size < 12) return;  // safety
    float*        total = (float*)d_ws;
    unsigned int* count = (unsigned int*)d_ws + 1;
    unsigned int* done  = (unsigned int*)d_ws + 2;

    hipMemsetAsync(d_ws, 0, 12, stream);  // zero accumulators (ws is poisoned)
    fused_kernel<<<BSZ, BSZ, 0, stream>>>(F, labels, epoch, total, count, done, out);
}